// Round 4
// baseline (415.121 us; speedup 1.0000x reference)
//
#include <hip/hip_runtime.h>
#include <hip/hip_fp16.h>

#define NN 20000
#define DD 128
#define EE 640000
#define TSEQ 12
#define CAP 128          // per-node CSR bucket capacity (Poisson(32), 11 sigma)
#define PADI 32          // cnt counter padding: one counter per 128-byte line

__device__ __forceinline__ void fma4(float4& acc, float a, const float4& w) {
  acc.x += a * w.x; acc.y += a * w.y; acc.z += a * w.z; acc.w += a * w.w;
}

__device__ __forceinline__ float4 h8_to_f4(uint2 v) {
  union { unsigned u; __half2 h; } a, b;
  a.u = v.x; b.u = v.y;
  float2 fa = __half22float2(a.h);
  float2 fb = __half22float2(b.h);
  return make_float4(fa.x, fa.y, fb.x, fb.y);
}

__device__ __forceinline__ uint2 f4_to_h8(float4 o) {
  union { unsigned u; __half2 h; } a, b;
  a.h = __floats2half2_rn(o.x, o.y);
  b.h = __floats2half2_rn(o.z, o.w);
  uint2 r; r.x = a.u; r.y = b.u;
  return r;
}

// ---------------- prep: zero cnt counters + all weight transposes ----------------
// blocks [0,625): cnt_pad zero;  blocks [625,1009): transposes
__global__ void k_prep(const float* __restrict__ fuse_W,
                       const float* __restrict__ gcn_W,
                       int* __restrict__ cnt_pad,
                       float* __restrict__ fuse_Wt,
                       float* __restrict__ gWt0,
                       __half* __restrict__ gWh) {
  int b = blockIdx.x;
  if (b < 625) {
    int i = b * 256 + threadIdx.x;
    ((int4*)cnt_pad)[i] = make_int4(0, 0, 0, 0);
  } else {
    int i = (b - 625) * 256 + threadIdx.x;
    if (i < 49152) {
      int k = i >> 7, d = i & 127;
      fuse_Wt[i] = fuse_W[d * 384 + k];
    } else if (i < 65536) {
      int j = i - 49152;
      int k = j >> 7, d = j & 127;
      gWt0[j] = gcn_W[d * 128 + k];
    } else if (i < 98304) {
      int j = i - 65536;
      int l = 1 + (j >> 14), jj = j & 16383;
      int k = jj >> 7, d = jj & 127;
      gWh[j] = (__half)gcn_W[l * 16384 + d * 128 + k];
    }
  }
}

// ---------------- mega: fused GEMM blocks [0,625) || edge blocks [625,3125) --------
// GEMM blocks now ALSO compute x0 = temp0 @ W0^T (fp32 weights, staged in 32-k
// chunks), storing xh0 UNSCALED fp16. x0 has no deg dependency because the GCN
// norm is later baked into the CSR weights (k_rescale), so the standalone
// k_gemm_x0 kernel (temp0 re-read + launch) is deleted entirely.
__global__ __launch_bounds__(256, 4) void k_mega(
    const float* __restrict__ emb, const float* __restrict__ demand,
    const float* __restrict__ supply,
    const float* __restrict__ fuse_Wt, const float* __restrict__ fuse_b,
    const float* __restrict__ gWt0,
    float* __restrict__ temp0, uint2* __restrict__ xh0,
    const int* __restrict__ src, const int* __restrict__ dst,
    const float* __restrict__ w,
    int* __restrict__ cnt_pad,
    uint2* __restrict__ csr)
{
  // 33 KB: fuse phase uses [0,8192) as 64x128 tile; x0 phase uses
  // [0,4224) as rows (stride 132, bank-conflict pad) and [4224,8320) as W0 chunk.
  __shared__ float Ws[8448];
  if (blockIdx.x < 625) {
    const int t  = threadIdx.x;
    const int dq = t & 15;
    const int ng = t >> 4;
    const int n_base = blockIdx.x * 32 + ng * 2;

    float4 acc0[2], acc1[2];
    #pragma unroll
    for (int i = 0; i < 2; ++i) {
      acc0[i] = make_float4(0.f, 0.f, 0.f, 0.f);
      acc1[i] = make_float4(0.f, 0.f, 0.f, 0.f);
    }

    // ---- fuse GEMM: 3 parts (emb, demand last step, supply last step), k=384 ----
    for (int p = 0; p < 3; ++p) {
      const float* ap; int as;
      if (p == 0)      { ap = emb;                  as = 128; }
      else if (p == 1) { ap = demand + 11 * 128;    as = TSEQ * 128; }
      else             { ap = supply + 11 * 128;    as = TSEQ * 128; }
      const float* rp0 = ap + (size_t)(n_base + 0) * as;
      const float* rp1 = ap + (size_t)(n_base + 1) * as;

      for (int c = 0; c < 2; ++c) {                // 2 chunks of 64 k
        const float4* wsrc = (const float4*)(fuse_Wt + (p * 128 + c * 64) * 128);
        float4* wdst = (float4*)Ws;
        #pragma unroll
        for (int it = 0; it < 8; ++it) wdst[it * 256 + t] = wsrc[it * 256 + t];
        __syncthreads();

        const int ks = c * 64;
        for (int k = 0; k < 64; k += 4) {
          float4 av0 = *(const float4*)(rp0 + ks + k);
          float4 av1 = *(const float4*)(rp1 + ks + k);
          #pragma unroll
          for (int j = 0; j < 4; ++j) {
            const float4 w0 = *(const float4*)&Ws[(k + j) * 128 + 4 * dq];
            const float4 w1 = *(const float4*)&Ws[(k + j) * 128 + 64 + 4 * dq];
            float a0 = (j == 0) ? av0.x : (j == 1) ? av0.y : (j == 2) ? av0.z : av0.w;
            float a1 = (j == 0) ? av1.x : (j == 1) ? av1.y : (j == 2) ? av1.z : av1.w;
            fma4(acc0[0], a0, w0); fma4(acc1[0], a0, w1);
            fma4(acc0[1], a1, w0); fma4(acc1[1], a1, w1);
          }
        }
        __syncthreads();
      }
    }

    // ---- bias, store temp0 (fp32), park rows in LDS for the x0 GEMM ----
    const float4 b0 = *(const float4*)&fuse_b[4 * dq];
    const float4 b1 = *(const float4*)&fuse_b[64 + 4 * dq];
    #pragma unroll
    for (int i = 0; i < 2; ++i) {
      const int r  = n_base + i;
      const int lr = ng * 2 + i;
      float4 o0 = make_float4(acc0[i].x + b0.x, acc0[i].y + b0.y,
                              acc0[i].z + b0.z, acc0[i].w + b0.w);
      float4 o1 = make_float4(acc1[i].x + b1.x, acc1[i].y + b1.y,
                              acc1[i].z + b1.z, acc1[i].w + b1.w);
      *(float4*)(temp0 + (size_t)r * DD + 4 * dq)      = o0;
      *(float4*)(temp0 + (size_t)r * DD + 64 + 4 * dq) = o1;
      *(float4*)&Ws[lr * 132 + 4 * dq]      = o0;
      *(float4*)&Ws[lr * 132 + 64 + 4 * dq] = o1;
    }

    // ---- x0 = rows @ W0^T (fp32 weights, 4 chunks of 32 k) ----
    float4 x00 = make_float4(0.f,0.f,0.f,0.f), x01 = x00, x10 = x00, x11 = x00;
    const int lr0 = ng * 2, lr1 = ng * 2 + 1;
    float* WsW = Ws + 4224;
    for (int c2 = 0; c2 < 4; ++c2) {
      const float4* wsrc = (const float4*)(gWt0 + c2 * 32 * 128);
      float4* wdst = (float4*)WsW;
      #pragma unroll
      for (int it = 0; it < 4; ++it) wdst[it * 256 + t] = wsrc[it * 256 + t];
      __syncthreads();
      const int ks = c2 * 32;
      for (int k = 0; k < 32; ++k) {
        const float a0 = Ws[lr0 * 132 + ks + k];
        const float a1 = Ws[lr1 * 132 + ks + k];
        const float4 w0 = *(const float4*)&WsW[k * 128 + 4 * dq];
        const float4 w1 = *(const float4*)&WsW[k * 128 + 64 + 4 * dq];
        fma4(x00, a0, w0); fma4(x01, a0, w1);
        fma4(x10, a1, w0); fma4(x11, a1, w1);
      }
      __syncthreads();
    }
    xh0[(size_t)(n_base + 0) * 32 + dq]      = f4_to_h8(x00);
    xh0[(size_t)(n_base + 0) * 32 + 16 + dq] = f4_to_h8(x01);
    xh0[(size_t)(n_base + 1) * 32 + dq]      = f4_to_h8(x10);
    xh0[(size_t)(n_base + 1) * 32 + 16 + dq] = f4_to_h8(x11);
  } else {
    int e = (blockIdx.x - 625) * 256 + threadIdx.x;   // exactly EE threads
    int s = src[e], d = dst[e];
    float we = w[e];
    int slot = atomicAdd(&cnt_pad[(size_t)d * PADI], 1);
    if (slot < CAP) csr[(size_t)d * CAP + slot] = make_uint2((unsigned)s, __float_as_uint(we));
  }
}

// ---------------- deg: dif[n] = rsqrt(1 + sum of bucket weights); compact cnt ------
__global__ __launch_bounds__(256, 8) void k_deg(
    const int* __restrict__ cnt_pad, const uint2* __restrict__ csr,
    float* __restrict__ dif, int* __restrict__ cntc)
{
  const int t = threadIdx.x;
  const int lane = t & 7;           // 8 lanes per node
  const int ng = t >> 3;            // 32 nodes per block
  const int n = blockIdx.x * 32 + ng;
  int m = cnt_pad[(size_t)n * PADI]; if (m > CAP) m = CAP;
  const size_t base = (size_t)n * CAP;
  float s = 0.f;
  for (int j = lane; j < m; j += 8) s += __uint_as_float(csr[base + j].y);
  s += __shfl_xor(s, 1);
  s += __shfl_xor(s, 2);
  s += __shfl_xor(s, 4);
  if (lane == 0) { dif[n] = rsqrtf(1.0f + s); cntc[n] = m; }
}

// ---------------- rescale: bake full GCN norm into CSR weights -------------------
// w'_e = w_e * dif[src] * dif[dst]. One-time pass so all 3 agg layers run the
// identical hot loop with zero extra per-edge work and xh stays unscaled.
__global__ __launch_bounds__(256, 8) void k_rescale(
    const int* __restrict__ cntc, const float* __restrict__ dif,
    uint2* __restrict__ csr)
{
  const int t = threadIdx.x;
  const int lane = t & 31;
  const int nl = t >> 5;            // 8 nodes per block
  const int n = blockIdx.x * 8 + nl;
  const int m = cntc[n];
  const float dn = dif[n];
  const size_t base = (size_t)n * CAP;
  for (int j = lane; j < m; j += 32) {
    uint2 c = csr[base + j];
    float wp = __uint_as_float(c.y) * dn * dif[c.x];
    ((unsigned*)csr)[(base + j) * 2 + 1] = __float_as_uint(wp);
  }
}

// ---------------- fused aggregation (+ optional next-layer GEMM) ----------------
// xh is UNSCALED; csr weights carry the full norm; self-loop term is dif^2 * x[n].
template<bool NEXT>
__global__ __launch_bounds__(256, 6) void k_agg_fused(
    const uint2* __restrict__ xh, const float* __restrict__ tin,
    const int* __restrict__ cntc, const uint2* __restrict__ csr,
    const float* __restrict__ dif, const float* __restrict__ bias,
    const uint2* __restrict__ Wh,      // fp16-packed next W, k-major [128][32 uint2]
    float* __restrict__ tout,
    uint2* __restrict__ xh_out)
{
  __shared__ float rows[NEXT ? 8 * 128 : 8];
  __shared__ uint2 Whs[NEXT ? 2048 : 8];   // 16 KB: one k=64 half of W

  const int t = threadIdx.x;
  const int dq = t & 31;          // uint2 column (4 dims)
  const int nl = t >> 5;          // 8 nodes per block
  const int n = blockIdx.x * 8 + nl;

  if constexpr (NEXT) {
    // stage first k-half early; latency hides under the gather below
    #pragma unroll
    for (int i = 0; i < 8; ++i) Whs[i * 256 + t] = Wh[i * 256 + t];
  }

  const float dfn = dif[n];
  const float d2 = dfn * dfn;
  float4 sv = h8_to_f4(xh[(size_t)n * 32 + dq]);   // self loop: dif^2 * x[n]
  float4 acc = make_float4(d2 * sv.x, d2 * sv.y, d2 * sv.z, d2 * sv.w);

  const size_t base = (size_t)n * CAP;
  const int m = cntc[n];
  int j = 0;
  for (; j + 16 <= m; j += 16) {
    uint2 c[16];
    #pragma unroll
    for (int u = 0; u < 16; ++u) c[u] = csr[base + j + u];
    uint2 v[16];
    #pragma unroll
    for (int u = 0; u < 16; ++u) v[u] = xh[(size_t)c[u].x * 32 + dq];
    #pragma unroll
    for (int u = 0; u < 16; ++u) fma4(acc, __uint_as_float(c[u].y), h8_to_f4(v[u]));
  }
  for (; j + 4 <= m; j += 4) {
    uint2 c[4];
    #pragma unroll
    for (int u = 0; u < 4; ++u) c[u] = csr[base + j + u];
    uint2 v[4];
    #pragma unroll
    for (int u = 0; u < 4; ++u) v[u] = xh[(size_t)c[u].x * 32 + dq];
    #pragma unroll
    for (int u = 0; u < 4; ++u) fma4(acc, __uint_as_float(c[u].y), h8_to_f4(v[u]));
  }
  for (; j < m; ++j) {
    uint2 c = csr[base + j];
    fma4(acc, __uint_as_float(c.y), h8_to_f4(xh[(size_t)c.x * 32 + dq]));
  }

  const float4 b4 = *(const float4*)&bias[4 * dq];
  const float4 ti = ((const float4*)tin)[(size_t)n * 32 + dq];
  float4 o;
  o.x = 0.9f * (acc.x + b4.x) + 0.1f * ti.x;
  o.y = 0.9f * (acc.y + b4.y) + 0.1f * ti.y;
  o.z = 0.9f * (acc.z + b4.z) + 0.1f * ti.z;
  o.w = 0.9f * (acc.w + b4.w) + 0.1f * ti.w;
  ((float4*)tout)[(size_t)n * 32 + dq] = o;

  if constexpr (NEXT) {
    *(float4*)&rows[nl * 128 + 4 * dq] = o;
    __syncthreads();            // covers rows store + Whs half-0 staging

    float4 x = make_float4(0.f, 0.f, 0.f, 0.f);
    const float* myrow = &rows[nl * 128];
    #pragma unroll 4
    for (int k = 0; k < 64; ++k) {
      fma4(x, myrow[k], h8_to_f4(Whs[k * 32 + dq]));
    }
    __syncthreads();            // all done with half 0
    #pragma unroll
    for (int i = 0; i < 8; ++i) Whs[i * 256 + t] = Wh[2048 + i * 256 + t];
    __syncthreads();            // half 1 staged
    #pragma unroll 4
    for (int k = 0; k < 64; ++k) {
      fma4(x, myrow[64 + k], h8_to_f4(Whs[k * 32 + dq]));
    }
    xh_out[(size_t)n * 32 + dq] = f4_to_h8(x);   // unscaled
  }
}

// ---------------- launch ----------------
extern "C" void kernel_launch(void* const* d_in, const int* in_sizes, int n_in,
                              void* d_out, int out_size, void* d_ws, size_t ws_size,
                              hipStream_t stream) {
  const float* demand = (const float*)d_in[0];
  const float* supply = (const float*)d_in[1];
  const int*   eidx   = (const int*)d_in[5];
  const float* eattr  = (const float*)d_in[6];
  const float* emb    = (const float*)d_in[10];
  const float* fuse_W = (const float*)d_in[11];
  const float* fuse_b = (const float*)d_in[12];
  const float* gcn_W  = (const float*)d_in[13];
  const float* gcn_b  = (const float*)d_in[14];
  float* outp = (float*)d_out;

  char* ws = (char*)d_ws;
  size_t o = 0;
  auto alloc = [&](size_t bytes) {
    char* p = ws + o;
    o += (bytes + 255) & ~(size_t)255;
    return p;
  };
  float*  dif     = (float*)alloc((size_t)NN * 4);          // compact, 80 KB
  int*    cntc    = (int*)alloc((size_t)NN * 4);            // compact, 80 KB
  int*    cnt_pad = (int*)alloc((size_t)NN * PADI * 4);     // 2.56 MB
  uint2*  csr     = (uint2*)alloc((size_t)NN * CAP * 8);
  float*  fuse_Wt = (float*)alloc((size_t)384 * 128 * 4);
  float*  gWt0    = (float*)alloc((size_t)128 * 128 * 4);
  __half* gWh     = (__half*)alloc((size_t)2 * 128 * 128 * 2);
  float*  temp0   = (float*)alloc((size_t)NN * DD * 4);
  float*  temp1   = (float*)alloc((size_t)NN * DD * 4);
  uint2*  xh_a    = (uint2*)alloc((size_t)NN * DD * 2);
  uint2*  xh_b    = (uint2*)alloc((size_t)NN * DD * 2);

  const int* srcv = eidx;        // edge_index[0]
  const int* dstv = eidx + EE;   // edge_index[1]

  k_prep<<<1009, 256, 0, stream>>>(fuse_W, gcn_W, cnt_pad, fuse_Wt, gWt0, gWh);

  k_mega<<<3125, 256, 0, stream>>>(emb, demand, supply, fuse_Wt, fuse_b, gWt0,
                                   temp0, xh_a, srcv, dstv, eattr, cnt_pad, csr);

  k_deg<<<625, 256, 0, stream>>>(cnt_pad, csr, dif, cntc);

  k_rescale<<<2500, 256, 0, stream>>>(cntc, dif, csr);

  const int AB = NN / 8;  // 2500
  k_agg_fused<true ><<<AB, 256, 0, stream>>>(xh_a, temp0, cntc, csr, dif, gcn_b,
                                             (const uint2*)gWh, temp1, xh_b);
  k_agg_fused<true ><<<AB, 256, 0, stream>>>(xh_b, temp1, cntc, csr, dif, gcn_b + 128,
                                             (const uint2*)(gWh + 16384), temp0, xh_a);
  k_agg_fused<false><<<AB, 256, 0, stream>>>(xh_a, temp0, cntc, csr, dif, gcn_b + 256,
                                             nullptr, outp, nullptr);
}

// Round 5
// 394.321 us; speedup vs baseline: 1.0527x; 1.0527x over previous
//
#include <hip/hip_runtime.h>
#include <hip/hip_fp16.h>

#define NN 20000
#define DD 128
#define EE 640000
#define TSEQ 12
#define CAP 128          // per-node CSR bucket capacity (Poisson(32), 11 sigma)
#define PADI 32          // cnt counter padding: one counter per 128-byte line

__device__ __forceinline__ void fma4(float4& acc, float a, const float4& w) {
  acc.x += a * w.x; acc.y += a * w.y; acc.z += a * w.z; acc.w += a * w.w;
}

__device__ __forceinline__ float4 h8_to_f4(uint2 v) {
  union { unsigned u; __half2 h; } a, b;
  a.u = v.x; b.u = v.y;
  float2 fa = __half22float2(a.h);
  float2 fb = __half22float2(b.h);
  return make_float4(fa.x, fa.y, fb.x, fb.y);
}

__device__ __forceinline__ uint2 f4_to_h8(float4 o) {
  union { unsigned u; __half2 h; } a, b;
  a.h = __floats2half2_rn(o.x, o.y);
  b.h = __floats2half2_rn(o.z, o.w);
  uint2 r; r.x = a.u; r.y = b.u;
  return r;
}

// decode packed CSR slot: hi 16 = src node id, lo 16 = fp16 weight bits
__device__ __forceinline__ float slot_w(unsigned c) {
  return __half2float(__ushort_as_half((unsigned short)(c & 0xffffu)));
}

// ---------------- prep: zero cnt counters + all weight transposes ----------------
// blocks [0,625): cnt_pad zero;  blocks [625,1009): transposes
__global__ void k_prep(const float* __restrict__ fuse_W,
                       const float* __restrict__ gcn_W,
                       int* __restrict__ cnt_pad,
                       float* __restrict__ fuse_Wt,
                       float* __restrict__ gWt0,
                       __half* __restrict__ gWh) {
  int b = blockIdx.x;
  if (b < 625) {
    int i = b * 256 + threadIdx.x;
    ((int4*)cnt_pad)[i] = make_int4(0, 0, 0, 0);
  } else {
    int i = (b - 625) * 256 + threadIdx.x;
    if (i < 49152) {
      int k = i >> 7, d = i & 127;
      fuse_Wt[i] = fuse_W[d * 384 + k];
    } else if (i < 65536) {
      int j = i - 49152;
      int k = j >> 7, d = j & 127;
      gWt0[j] = gcn_W[d * 128 + k];
    } else if (i < 98304) {
      int j = i - 65536;
      int l = 1 + (j >> 14), jj = j & 16383;
      int k = jj >> 7, d = jj & 127;
      gWh[j] = (__half)gcn_W[l * 16384 + d * 128 + k];
    }
  }
}

// ---------------- fuse GEMM body: temp0[n][d] = concat-row @ fuse_Wt (+bias) ------
__device__ __forceinline__ void fuse_gemm_body(
    float* Ws, int gb,
    const float* a0, const float* a1, const float* a2,
    const float* Wt, const float* bias, float* outf)
{
  const int t = threadIdx.x;
  const int dq = t & 15;
  const int ng = t >> 4;
  const int n_base = gb * 32 + ng * 2;

  float4 acc0[2], acc1[2];
  #pragma unroll
  for (int i = 0; i < 2; ++i) {
    acc0[i] = make_float4(0.f, 0.f, 0.f, 0.f);
    acc1[i] = make_float4(0.f, 0.f, 0.f, 0.f);
  }

  for (int p = 0; p < 3; ++p) {
    const float* ap; int as;
    if (p == 0)      { ap = a0; as = 128; }
    else if (p == 1) { ap = a1; as = TSEQ * 128; }
    else             { ap = a2; as = TSEQ * 128; }
    const float* rp0 = ap + (size_t)(n_base + 0) * as;
    const float* rp1 = ap + (size_t)(n_base + 1) * as;

    for (int c = 0; c < 2; ++c) {                // 2 chunks of 64 k
      const float4* wsrc = (const float4*)(Wt + (p * 128 + c * 64) * 128);
      float4* wdst = (float4*)Ws;
      #pragma unroll
      for (int it = 0; it < 8; ++it) wdst[it * 256 + t] = wsrc[it * 256 + t];
      __syncthreads();

      const int ks = c * 64;
      for (int k = 0; k < 64; k += 4) {
        float4 av0 = *(const float4*)(rp0 + ks + k);
        float4 av1 = *(const float4*)(rp1 + ks + k);
        #pragma unroll
        for (int j = 0; j < 4; ++j) {
          const float4 w0 = *(const float4*)&Ws[(k + j) * 128 + 4 * dq];
          const float4 w1 = *(const float4*)&Ws[(k + j) * 128 + 64 + 4 * dq];
          float a0v = (j == 0) ? av0.x : (j == 1) ? av0.y : (j == 2) ? av0.z : av0.w;
          float a1v = (j == 0) ? av1.x : (j == 1) ? av1.y : (j == 2) ? av1.z : av1.w;
          fma4(acc0[0], a0v, w0); fma4(acc1[0], a0v, w1);
          fma4(acc0[1], a1v, w0); fma4(acc1[1], a1v, w1);
        }
      }
      __syncthreads();
    }
  }

  const float4 b0 = *(const float4*)&bias[4 * dq];
  const float4 b1 = *(const float4*)&bias[64 + 4 * dq];
  #pragma unroll
  for (int i = 0; i < 2; ++i) {
    const int r = n_base + i;
    float4 o0 = make_float4(acc0[i].x + b0.x, acc0[i].y + b0.y,
                            acc0[i].z + b0.z, acc0[i].w + b0.w);
    float4 o1 = make_float4(acc1[i].x + b1.x, acc1[i].y + b1.y,
                            acc1[i].z + b1.z, acc1[i].w + b1.w);
    *(float4*)(outf + (size_t)r * DD + 4 * dq)      = o0;
    *(float4*)(outf + (size_t)r * DD + 64 + 4 * dq) = o1;
  }
}

// ---------------- mega: fuse-GEMM blocks [0,625) || edge blocks [625,3125) ----------
// Edge slot packed to 4B: (src<<16)|fp16(w). A 32-edge bucket = one 128B line,
// halving the scatter dirty-line traffic (~41 -> ~20 MB) that sets this
// kernel's duration at the ~1 TB/s scattered-traffic wall.
__global__ __launch_bounds__(256, 4) void k_mega(
    const float* __restrict__ emb, const float* __restrict__ demand,
    const float* __restrict__ supply,
    const float* __restrict__ fuse_Wt, const float* __restrict__ fuse_b,
    float* __restrict__ temp0,
    const int* __restrict__ src, const int* __restrict__ dst,
    const float* __restrict__ w,
    int* __restrict__ cnt_pad,
    unsigned* __restrict__ csr)
{
  __shared__ float Ws[64 * 128];    // 32 KB (edge blocks carry it unused)
  if (blockIdx.x < 625) {
    fuse_gemm_body(Ws, blockIdx.x,
                   emb, demand + 11 * 128, supply + 11 * 128,
                   fuse_Wt, fuse_b, temp0);
  } else {
    int e = (blockIdx.x - 625) * 256 + threadIdx.x;   // exactly EE threads
    int s = src[e], d = dst[e];
    float we = w[e];
    int slot = atomicAdd(&cnt_pad[(size_t)d * PADI], 1);
    if (slot < CAP)
      csr[(size_t)d * CAP + slot] =
          ((unsigned)s << 16) | (unsigned)__half_as_ushort(__float2half_rn(we));
  }
}

// ---------------- x0+deg: dif/cntc for own 32 nodes, then xh = di*(temp0 @ W0^T) ---
// deg phase folded in (each block's nodes == its GEMM rows, bucket sums are local),
// deleting the separate k_deg launch. difs passed to epilogue via LDS.
__global__ __launch_bounds__(256, 8) void k_x0deg(
    const float* __restrict__ temp0, const float* __restrict__ gWt0,
    const int* __restrict__ cnt_pad, const unsigned* __restrict__ csr,
    float* __restrict__ dif, int* __restrict__ cntc,
    uint2* __restrict__ outh)
{
  __shared__ float Ws[32 * 128];   // 16 KB W chunk
  __shared__ float difs[32];

  const int t = threadIdx.x;

  // ---- deg: 8 lanes per node, 32 nodes (== this block's GEMM rows) ----
  {
    const int lane = t & 7;
    const int ng8 = t >> 3;
    const int n = blockIdx.x * 32 + ng8;
    int m = cnt_pad[(size_t)n * PADI]; if (m > CAP) m = CAP;
    const size_t base = (size_t)n * CAP;
    float s = 0.f;
    for (int j = lane; j < m; j += 8) s += slot_w(csr[base + j]);
    s += __shfl_xor(s, 1);
    s += __shfl_xor(s, 2);
    s += __shfl_xor(s, 4);
    if (lane == 0) {
      float df = rsqrtf(1.0f + s);
      dif[n] = df; cntc[n] = m; difs[ng8] = df;
    }
  }
  __syncthreads();

  // ---- GEMM: rows @ W0^T, 4 chunks of 32 k ----
  const int dq = t & 15;
  const int ng = t >> 4;
  const int n_base = blockIdx.x * 32 + ng * 2;
  const float* rp0 = temp0 + (size_t)(n_base + 0) * DD;
  const float* rp1 = temp0 + (size_t)(n_base + 1) * DD;

  float4 a00 = make_float4(0.f,0.f,0.f,0.f), a01 = a00, a10 = a00, a11 = a00;
  for (int c = 0; c < 4; ++c) {
    const float4* wsrc = (const float4*)(gWt0 + c * 32 * 128);
    float4* wdst = (float4*)Ws;
    #pragma unroll
    for (int it = 0; it < 4; ++it) wdst[it * 256 + t] = wsrc[it * 256 + t];
    __syncthreads();

    const int ks = c * 32;
    for (int k = 0; k < 32; k += 4) {
      float4 av0 = *(const float4*)(rp0 + ks + k);
      float4 av1 = *(const float4*)(rp1 + ks + k);
      #pragma unroll
      for (int j = 0; j < 4; ++j) {
        const float4 w0 = *(const float4*)&Ws[(k + j) * 128 + 4 * dq];
        const float4 w1 = *(const float4*)&Ws[(k + j) * 128 + 64 + 4 * dq];
        float a0v = (j == 0) ? av0.x : (j == 1) ? av0.y : (j == 2) ? av0.z : av0.w;
        float a1v = (j == 0) ? av1.x : (j == 1) ? av1.y : (j == 2) ? av1.z : av1.w;
        fma4(a00, a0v, w0); fma4(a01, a0v, w1);
        fma4(a10, a1v, w0); fma4(a11, a1v, w1);
      }
    }
    __syncthreads();
  }

  const float d0 = difs[ng * 2 + 0];
  const float d1 = difs[ng * 2 + 1];
  a00.x *= d0; a00.y *= d0; a00.z *= d0; a00.w *= d0;
  a01.x *= d0; a01.y *= d0; a01.z *= d0; a01.w *= d0;
  a10.x *= d1; a10.y *= d1; a10.z *= d1; a10.w *= d1;
  a11.x *= d1; a11.y *= d1; a11.z *= d1; a11.w *= d1;
  outh[(size_t)(n_base + 0) * 32 + dq]      = f4_to_h8(a00);
  outh[(size_t)(n_base + 0) * 32 + 16 + dq] = f4_to_h8(a01);
  outh[(size_t)(n_base + 1) * 32 + dq]      = f4_to_h8(a10);
  outh[(size_t)(n_base + 1) * 32 + 16 + dq] = f4_to_h8(a11);
}

// ---------------- fused aggregation (+ optional next-layer GEMM) ----------------
// xh rows are pre-scaled by dinv[src]; per-edge fp16 weight decoded from packed
// slot; epilogue applies dinv[dst]. Self loop: xh[n] already has dinv[n], gets
// the second dinv[n] at the epilogue (weight 1).
template<bool NEXT>
__global__ __launch_bounds__(256, 6) void k_agg_fused(
    const uint2* __restrict__ xh, const float* __restrict__ tin,
    const int* __restrict__ cntc, const unsigned* __restrict__ csr,
    const float* __restrict__ dif, const float* __restrict__ bias,
    const uint2* __restrict__ Wh,      // fp16-packed next W, k-major [128][32 uint2]
    float* __restrict__ tout,
    uint2* __restrict__ xh_out)
{
  __shared__ float rows[NEXT ? 8 * 128 : 8];
  __shared__ uint2 Whs[NEXT ? 2048 : 8];   // 16 KB: one k=64 half of W

  const int t = threadIdx.x;
  const int dq = t & 31;          // uint2 column (4 dims)
  const int nl = t >> 5;          // 8 nodes per block
  const int n = blockIdx.x * 8 + nl;

  if constexpr (NEXT) {
    // stage first k-half early; latency hides under the gather below
    #pragma unroll
    for (int i = 0; i < 8; ++i) Whs[i * 256 + t] = Wh[i * 256 + t];
  }

  const float di = rsqrtf(1.0f) * dif[n];   // dinv[dst]
  float4 acc = h8_to_f4(xh[(size_t)n * 32 + dq]);   // self loop (weight 1)

  const size_t base = (size_t)n * CAP;
  const int m = cntc[n];
  int j = 0;
  for (; j + 16 <= m; j += 16) {
    unsigned c[16];
    #pragma unroll
    for (int u = 0; u < 16; ++u) c[u] = csr[base + j + u];
    uint2 v[16];
    #pragma unroll
    for (int u = 0; u < 16; ++u) v[u] = xh[(size_t)(c[u] >> 16) * 32 + dq];
    #pragma unroll
    for (int u = 0; u < 16; ++u) fma4(acc, slot_w(c[u]), h8_to_f4(v[u]));
  }
  for (; j + 4 <= m; j += 4) {
    unsigned c[4];
    #pragma unroll
    for (int u = 0; u < 4; ++u) c[u] = csr[base + j + u];
    uint2 v[4];
    #pragma unroll
    for (int u = 0; u < 4; ++u) v[u] = xh[(size_t)(c[u] >> 16) * 32 + dq];
    #pragma unroll
    for (int u = 0; u < 4; ++u) fma4(acc, slot_w(c[u]), h8_to_f4(v[u]));
  }
  for (; j < m; ++j) {
    unsigned c = csr[base + j];
    fma4(acc, slot_w(c), h8_to_f4(xh[(size_t)(c >> 16) * 32 + dq]));
  }

  const float4 b4 = *(const float4*)&bias[4 * dq];
  const float4 ti = ((const float4*)tin)[(size_t)n * 32 + dq];
  float4 o;
  o.x = 0.9f * (di * acc.x + b4.x) + 0.1f * ti.x;
  o.y = 0.9f * (di * acc.y + b4.y) + 0.1f * ti.y;
  o.z = 0.9f * (di * acc.z + b4.z) + 0.1f * ti.z;
  o.w = 0.9f * (di * acc.w + b4.w) + 0.1f * ti.w;
  ((float4*)tout)[(size_t)n * 32 + dq] = o;

  if constexpr (NEXT) {
    *(float4*)&rows[nl * 128 + 4 * dq] = o;
    __syncthreads();            // covers rows store + Whs half-0 staging

    float4 x = make_float4(0.f, 0.f, 0.f, 0.f);
    const float* myrow = &rows[nl * 128];
    #pragma unroll 4
    for (int k = 0; k < 64; ++k) {
      fma4(x, myrow[k], h8_to_f4(Whs[k * 32 + dq]));
    }
    __syncthreads();            // all done with half 0
    #pragma unroll
    for (int i = 0; i < 8; ++i) Whs[i * 256 + t] = Wh[2048 + i * 256 + t];
    __syncthreads();            // half 1 staged
    #pragma unroll 4
    for (int k = 0; k < 64; ++k) {
      fma4(x, myrow[64 + k], h8_to_f4(Whs[k * 32 + dq]));
    }
    x.x *= di; x.y *= di; x.z *= di; x.w *= di;
    xh_out[(size_t)n * 32 + dq] = f4_to_h8(x);
  }
}

// ---------------- launch ----------------
extern "C" void kernel_launch(void* const* d_in, const int* in_sizes, int n_in,
                              void* d_out, int out_size, void* d_ws, size_t ws_size,
                              hipStream_t stream) {
  const float* demand = (const float*)d_in[0];
  const float* supply = (const float*)d_in[1];
  const int*   eidx   = (const int*)d_in[5];
  const float* eattr  = (const float*)d_in[6];
  const float* emb    = (const float*)d_in[10];
  const float* fuse_W = (const float*)d_in[11];
  const float* fuse_b = (const float*)d_in[12];
  const float* gcn_W  = (const float*)d_in[13];
  const float* gcn_b  = (const float*)d_in[14];
  float* outp = (float*)d_out;

  char* ws = (char*)d_ws;
  size_t o = 0;
  auto alloc = [&](size_t bytes) {
    char* p = ws + o;
    o += (bytes + 255) & ~(size_t)255;
    return p;
  };
  float*    dif     = (float*)alloc((size_t)NN * 4);          // compact, 80 KB
  int*      cntc    = (int*)alloc((size_t)NN * 4);            // compact, 80 KB
  int*      cnt_pad = (int*)alloc((size_t)NN * PADI * 4);     // 2.56 MB
  unsigned* csr     = (unsigned*)alloc((size_t)NN * CAP * 4); // 10.24 MB (packed)
  float*    fuse_Wt = (float*)alloc((size_t)384 * 128 * 4);
  float*    gWt0    = (float*)alloc((size_t)128 * 128 * 4);
  __half*   gWh     = (__half*)alloc((size_t)2 * 128 * 128 * 2);
  float*    temp0   = (float*)alloc((size_t)NN * DD * 4);
  float*    temp1   = (float*)alloc((size_t)NN * DD * 4);
  uint2*    xh_a    = (uint2*)alloc((size_t)NN * DD * 2);
  uint2*    xh_b    = (uint2*)alloc((size_t)NN * DD * 2);

  const int* srcv = eidx;        // edge_index[0]
  const int* dstv = eidx + EE;   // edge_index[1]

  k_prep<<<1009, 256, 0, stream>>>(fuse_W, gcn_W, cnt_pad, fuse_Wt, gWt0, gWh);

  k_mega<<<3125, 256, 0, stream>>>(emb, demand, supply, fuse_Wt, fuse_b, temp0,
                                   srcv, dstv, eattr, cnt_pad, csr);

  k_x0deg<<<625, 256, 0, stream>>>(temp0, gWt0, cnt_pad, csr, dif, cntc, xh_a);

  const int AB = NN / 8;  // 2500
  k_agg_fused<true ><<<AB, 256, 0, stream>>>(xh_a, temp0, cntc, csr, dif, gcn_b,
                                             (const uint2*)gWh, temp1, xh_b);
  k_agg_fused<true ><<<AB, 256, 0, stream>>>(xh_b, temp1, cntc, csr, dif, gcn_b + 128,
                                             (const uint2*)(gWh + 16384), temp0, xh_a);
  k_agg_fused<false><<<AB, 256, 0, stream>>>(xh_a, temp0, cntc, csr, dif, gcn_b + 256,
                                             nullptr, outp, nullptr);
}